// Round 5
// baseline (206.510 us; speedup 1.0000x reference)
//
#include <hip/hip_runtime.h>
#include <math.h>
#include <stdint.h>

#define B_ 4096
#define T_ 128
#define S_ 16
#define C_ 128
#define L_ 33            // 2*S+1
#define NSLOT 17         // blank + 16 targets
#define NELEM (T_ * NSLOT)    // 2176 = 34 * 64
#define LDSF  (NELEM + 52)    // pad: ring reads up to idx 130*17+16 = 2226
#define NEGV (-1e30f)
#define LOG2E 1.4426950408889634f
#define LN2 0.6931471805599453f
#define NEGB (NEGV * LOG2E)

__device__ __forceinline__ float hexp2(float x) { return __builtin_amdgcn_exp2f(x); }
__device__ __forceinline__ float hlog2(float x) { return __builtin_amdgcn_logf(x); }

// monotonic float->uint map: a > b (float) <=> fkey(a) > fkey(b) (uint)
__device__ __forceinline__ unsigned fkey(float v) {
    unsigned u = __float_as_uint(v);
    return (u & 0x80000000u) ? ~u : (u | 0x80000000u);
}

typedef const __attribute__((address_space(1))) unsigned int* gas_t;
typedef __attribute__((address_space(3))) unsigned int* las_t;

// One wave per block, one batch element per wave. Last block reduces.
__global__ __launch_bounds__(64) void ctc_fused_kernel(
        const float* __restrict__ pred,   // (B, T, C) log-probs
        const float* __restrict__ lab,    // (B, S, C)
        float* __restrict__ out_b,        // ws[0..B): nll/S per element
        int* __restrict__ counter,        // ws + B, zeroed per call
        float* __restrict__ out) {        // d_out[0]
    const int b = blockIdx.x;
    const int lane = threadIdx.x;

    __shared__ int   cls_tab[NSLOT];
    __shared__ float lps[LDSF];           // flat [t*17 + slot]

    // ---- Phase A: targets[s] = argmax_c lab[b,s,c], first-index tie-break ----
    // Two rows per pass (lanes 0-31 row 2sp, lanes 32-63 row 2sp+1), float4 loads.
    const int half = lane >> 5;
    const int li   = lane & 31;
    const float4* lrow4 =
        (const float4*)(lab + (size_t)b * S_ * C_ + (size_t)half * C_);
    float4 q[8];
    #pragma unroll
    for (int sp = 0; sp < 8; ++sp)
        q[sp] = lrow4[(size_t)sp * 2 * (C_ / 4) + li];   // 8 indep 16B loads

    if (lane == 0) cls_tab[0] = 0;        // blank class
    #pragma unroll
    for (int sp = 0; sp < 8; ++sp) {
        float vals[4] = {q[sp].x, q[sp].y, q[sp].z, q[sp].w};
        unsigned long long key = 0;       // fkey(v)<<32 | ~idx : max == (max v, min idx)
        #pragma unroll
        for (int k = 0; k < 4; ++k) {
            unsigned long long kk =
                ((unsigned long long)fkey(vals[k]) << 32) | (unsigned)(~(li * 4 + k));
            if (kk > key) key = kk;       // strict >, k ascending: first index wins
        }
        #pragma unroll
        for (int off = 16; off >= 1; off >>= 1) {
            unsigned long long ok = __shfl_xor(key, off, 64);  // stays within half
            if (ok > key) key = ok;
        }
        if (li == 0) cls_tab[1 + sp * 2 + half] = (int)(~(unsigned)key) & 127;
    }
    asm volatile("s_waitcnt lgkmcnt(0)" ::: "memory");   // cls_tab visible in-wave

    // ---- Phase B: stage lp[t][slot] into LDS, two 64-timestep chunks ----
    // e = i*64+lane -> t = e/17, slot = e%17; LDS dest linear in lane.
    const float* pb = pred + (size_t)b * T_ * C_;
    #pragma unroll
    for (int i = 0; i < 17; ++i) {        // chunk A: t in [0,64)
        unsigned e = i * 64 + lane;
        unsigned t = e / NSLOT;
        unsigned s = e - t * NSLOT;
        const float* src = pb + (size_t)t * C_ + cls_tab[s];
        __builtin_amdgcn_global_load_lds((gas_t)src, (las_t)(lps + i * 64), 4, 0, 0);
    }
    __builtin_amdgcn_sched_barrier(0);    // pin issue order: A fully before B
    #pragma unroll
    for (int i = 17; i < 34; ++i) {       // chunk B: t in [64,128)
        unsigned e = i * 64 + lane;
        unsigned t = e / NSLOT;
        unsigned s = e - t * NSLOT;
        const float* src = pb + (size_t)t * C_ + cls_tab[s];
        __builtin_amdgcn_global_load_lds((gas_t)src, (las_t)(lps + i * 64), 4, 0, 0);
    }
    __builtin_amdgcn_sched_barrier(0);

    // ---- Phase C: alpha recursion in log2 domain ----
    const int l = lane;
    int cidx = 0;
    bool skipv = false;
    if (l < L_ && (l & 1)) {
        cidx = 1 + ((l - 1) >> 1);
        if (l >= 3) skipv = (cls_tab[cidx] != cls_tab[cidx - 1]);
    }
    const bool has2 = (l >= 1);

    asm volatile("s_waitcnt vmcnt(17)" ::: "memory");    // chunk A ready

    float beta = (l <= 1) ? lps[cidx] * LOG2E : NEGB;    // t = 0
    float lpA = lps[1 * NSLOT + cidx];
    float lpB = lps[2 * NSLOT + cidx];
    float lpC = lps[3 * NSLOT + cidx];

    #pragma unroll 4
    for (int t = 1; t <= 60; ++t) {       // reads up to (63)*17: chunk A only
        float lp = lpA; lpA = lpB; lpB = lpC;
        lpC = lps[(t + 3) * NSLOT + cidx];
        float a2 = __shfl_up(beta, 1, 64);
        float a3 = __shfl_up(beta, 2, 64);
        a2 = has2  ? a2 : NEGB;
        a3 = skipv ? a3 : NEGB;
        float m = fmaxf(fmaxf(beta, a2), a3);            // v_max3_f32
        float s = hexp2(beta - m) + hexp2(a2 - m) + hexp2(a3 - m);
        beta = fmaf(lp, LOG2E, m + hlog2(s));
    }

    asm volatile("s_waitcnt vmcnt(0)" ::: "memory");     // chunk B ready

    #pragma unroll 4
    for (int t = 61; t < T_; ++t) {       // pad region covers reads to t+3 = 130
        float lp = lpA; lpA = lpB; lpB = lpC;
        lpC = lps[(t + 3) * NSLOT + cidx];
        float a2 = __shfl_up(beta, 1, 64);
        float a3 = __shfl_up(beta, 2, 64);
        a2 = has2  ? a2 : NEGB;
        a3 = skipv ? a3 : NEGB;
        float m = fmaxf(fmaxf(beta, a2), a3);
        float s = hexp2(beta - m) + hexp2(a2 - m) + hexp2(a3 - m);
        beta = fmaf(lp, LOG2E, m + hlog2(s));
    }

    float b31 = __shfl(beta, L_ - 2, 64);
    float b32 = __shfl(beta, L_ - 1, 64);
    float m2 = fmaxf(b31, b32);
    float nll = -(m2 + hlog2(hexp2(b31 - m2) + hexp2(b32 - m2))) * LN2;
    if (!isfinite(nll)) nll = 0.0f;       // zero_infinity
    float val = nll * (1.0f / (float)S_);
    if (lane == 0)
        __hip_atomic_store(&out_b[b], val, __ATOMIC_RELAXED, __HIP_MEMORY_SCOPE_AGENT);

    // ---- Phase D: last-arriving block does the deterministic mean ----
    int old = 0;
    if (lane == 0)
        old = __hip_atomic_fetch_add(counter, 1, __ATOMIC_ACQ_REL,
                                     __HIP_MEMORY_SCOPE_AGENT);
    old = __shfl(old, 0, 64);
    if (old == B_ - 1) {                  // exactly one block; result is
        __threadfence();                  // block-identity-independent
        float s = 0.f;
        #pragma unroll
        for (int i = 0; i < B_ / 64; ++i) // fixed order: deterministic
            s += __hip_atomic_load(&out_b[lane + i * 64], __ATOMIC_RELAXED,
                                   __HIP_MEMORY_SCOPE_AGENT);
        #pragma unroll
        for (int off = 1; off < 64; off <<= 1)
            s += __shfl_xor(s, off, 64);  // fixed butterfly order
        if (lane == 0) *out = s * (1.0f / (float)B_);
    }
}

extern "C" void kernel_launch(void* const* d_in, const int* in_sizes, int n_in,
                              void* d_out, int out_size, void* d_ws, size_t ws_size,
                              hipStream_t stream) {
    const float* pred = (const float*)d_in[0];  // (B,T,C) fp32
    const float* lab  = (const float*)d_in[1];  // (B,S,C) fp32
    float* ws = (float*)d_ws;                   // [0,B): partials; +B: counter
    int* counter = (int*)(ws + B_);
    hipMemsetAsync(counter, 0, sizeof(int), stream);   // graph-capturable memset node
    ctc_fused_kernel<<<B_, 64, 0, stream>>>(pred, lab, ws, counter, (float*)d_out);
}